// Round 2
// 2347.807 us; speedup vs baseline: 1.0483x; 1.0483x over previous
//
#include <hip/hip_runtime.h>
#include <math.h>

#define HID   256
#define SEQ   512
#define BATCH 256
#define NPRED 64
#define NOUT  3
#define KP2   264    // fp16 k-pairs of padded xcat2: [x0,x1,x2,0, ctx(256), h(256), pad] / 2
#define GATES 1024

typedef unsigned int u32;
typedef _Float16 half2_t __attribute__((ext_vector_type(2)));
typedef __fp16   fp16x2_t __attribute__((ext_vector_type(2)));

__device__ __forceinline__ float sigmoidf_(float x) { return 1.0f / (1.0f + __expf(-x)); }
__device__ __forceinline__ float tanhf_(float x)    { return 1.0f - 2.0f / (__expf(2.0f * x) + 1.0f); }

// ---- fp16 pack / dot helpers ------------------------------------------------
__device__ __forceinline__ float fdot2_(u32 a, u32 b, float c) {
#if __has_builtin(__builtin_amdgcn_fdot2)
    union { u32 u; half2_t h; } x, y; x.u = a; y.u = b;
    return __builtin_amdgcn_fdot2(x.h, y.h, c, false);
#else
    union { u32 u; _Float16 h[2]; } x, y; x.u = a; y.u = b;
    return c + (float)x.h[0] * (float)y.h[0] + (float)x.h[1] * (float)y.h[1];
#endif
}
__device__ __forceinline__ u32 pkrtz_(float a, float b) {
#if __has_builtin(__builtin_amdgcn_cvt_pkrtz)
    union { fp16x2_t h; u32 u; } c; c.h = __builtin_amdgcn_cvt_pkrtz(a, b); return c.u;
#else
    union { _Float16 h[2]; u32 u; } c; c.h[0] = (_Float16)a; c.h[1] = (_Float16)b; return c.u;
#endif
}
__device__ __forceinline__ u32 pkrne_(float a, float b) {   // RNE pack (prep only)
    union { _Float16 h[2]; u32 u; } c; c.h[0] = (_Float16)a; c.h[1] = (_Float16)b; return c.u;
}
// (a.lo16, b.lo16) and (a.hi16, b.hi16)
__device__ __forceinline__ u32 lo_lo(u32 a, u32 b) {
#if __has_builtin(__builtin_amdgcn_perm)
    return __builtin_amdgcn_perm(b, a, 0x05040100u);
#else
    return (a & 0xffffu) | (b << 16);
#endif
}
__device__ __forceinline__ u32 hi_hi(u32 a, u32 b) {
#if __has_builtin(__builtin_amdgcn_perm)
    return __builtin_amdgcn_perm(b, a, 0x07060302u);
#else
    return (a >> 16) | (b & 0xffff0000u);
#endif
}

// ---------------------------------------------------------------------------
// prep_wc: Wcat column for padded-xcat2 k:
//   k<3: W_ih[:,k] (x_in) | k==3: 0 | 4<=k<260: W_ih[:,k-1] (ctx) |
//   260<=k<516: W_hh[:,k-260] (h) | else 0.  fp16 pairs, comp q = gate 4j+q.
// ---------------------------------------------------------------------------
__device__ __forceinline__ float colval_(const float* W_ih, const float* W_hh, int g, int k) {
    if (k < 3)   return W_ih[g * 259 + k];
    if (k == 3)  return 0.f;
    if (k < 260) return W_ih[g * 259 + (k - 1)];
    if (k < 516) return W_hh[g * HID + (k - 260)];
    return 0.f;
}
__global__ void prep_wc(const float* __restrict__ W_ih,
                        const float* __restrict__ W_hh,
                        uint4* __restrict__ Wc2) {
    const int p = blockIdx.x;        // 0..263 k-pair
    const int j = threadIdx.x;       // 0..255
    u32 comp[4];
    #pragma unroll
    for (int q = 0; q < 4; ++q) {
        const int g = 4 * j + q;
        comp[q] = pkrne_(colval_(W_ih, W_hh, g, 2 * p),
                         colval_(W_ih, W_hh, g, 2 * p + 1));
    }
    Wc2[p * 256 + j] = make_uint4(comp[0], comp[1], comp[2], comp[3]);
}

// ---------------------------------------------------------------------------
// prep_ma: MaT[k][j] = sum_m Wa[m][k]*Ua[m][j]; fp16 pairs:
// Ma2[k4][j].x = pk(MaT[4k4], MaT[4k4+1]); .y = (+2,+3)
// ---------------------------------------------------------------------------
__global__ void prep_ma(const float* __restrict__ Wa,
                        const float* __restrict__ Ua,
                        uint2* __restrict__ Ma2) {
    const int k4 = blockIdx.x;       // 0..63
    const int j  = threadIdx.x;      // 0..255
    float acc[4] = {0.f, 0.f, 0.f, 0.f};
    for (int m = 0; m < HID; ++m) {
        const float ua = Ua[m * HID + j];
        #pragma unroll
        for (int q = 0; q < 4; ++q)
            acc[q] += Wa[m * HID + 4 * k4 + q] * ua;
    }
    Ma2[k4 * 256 + j] = make_uint2(pkrne_(acc[0], acc[1]), pkrne_(acc[2], acc[3]));
}

__global__ void prep_misc(const float* __restrict__ b_ih,
                          const float* __restrict__ b_hh,
                          const float* __restrict__ ba,
                          const float* __restrict__ Ua,
                          float* __restrict__ bias_g,
                          float* __restrict__ v0) {
    const int t = threadIdx.x;
    if (t < GATES) bias_g[t] = b_ih[t] + b_hh[t];
    if (t < HID) {
        float acc = 0.f;
        for (int m = 0; m < HID; ++m) acc += ba[m] * Ua[m * HID + t];
        v0[t] = acc;
    }
}

__global__ void prep_ench(const float* __restrict__ enc, u32* __restrict__ ench) {
    const int total = BATCH * SEQ * HID / 4;
    for (int i = blockIdx.x * blockDim.x + threadIdx.x; i < total;
         i += gridDim.x * blockDim.x) {
        const float4 f = ((const float4*)enc)[i];
        ((uint2*)ench)[i] = make_uint2(pkrne_(f.x, f.y), pkrne_(f.z, f.w));
    }
}

// ---- enc loads (fp16 path or fp32 fallback with on-the-fly pack) ----------
template <bool EH>
__device__ __forceinline__ uint4 ld4e_(const u32* ph, const float* pf, int off /*u32 idx*/) {
    if constexpr (EH) {
        return *(const uint4*)(ph + off);
    } else {
        const float4 f0 = *(const float4*)(pf + (off << 1));
        const float4 f1 = *(const float4*)(pf + (off << 1) + 4);
        return make_uint4(pkrtz_(f0.x, f0.y), pkrtz_(f0.z, f0.w),
                          pkrtz_(f1.x, f1.y), pkrtz_(f1.z, f1.w));
    }
}
template <bool EH>
__device__ __forceinline__ uint2 ld2e_(const u32* ph, const float* pf, int off) {
    if constexpr (EH) {
        return *(const uint2*)(ph + off);
    } else {
        const float4 f = *(const float4*)(pf + (off << 1));
        return make_uint2(pkrtz_(f.x, f.y), pkrtz_(f.z, f.w));
    }
}

// ---- P1: vq[j] = v0[j] + sum_k MaT[k][j] h[k]; fp16 dot2, threads j<256 ---
__device__ __forceinline__ void p1_body(const uint2* __restrict__ Ma2,
                                        const float* __restrict__ v0,
                                        const u32* s_xh, u32* s_vqh, int j) {
    float a0 = 0.f, a1 = 0.f;
    #pragma unroll 8
    for (int p2 = 0; p2 < 64; ++p2) {
        const uint2 ma = Ma2[(p2 << 8) + j];
        const uint2 hh = *(const uint2*)&s_xh[130 + (p2 << 1)];
        a0 = fdot2_(ma.x, hh.x, a0);
        a1 = fdot2_(ma.y, hh.y, a1);
    }
    float acc = v0[j] + a0 + a1;
    const float accN = __shfl_xor(acc, 1);
    if (!(j & 1)) s_vqh[j >> 1] = pkrtz_(acc, accN);
}

// ---------------------------------------------------------------------------
// Persistent decoder: one 1024-thread block per batch element, 7 barriers/step.
// ---------------------------------------------------------------------------
template <bool EH>
__global__ __launch_bounds__(1024)
void decoder_kernel(const float* __restrict__ enc,     // [B,S,H] fp32
                    const u32*   __restrict__ ench,    // [B,S,H] fp16 pairs
                    const float* __restrict__ h0,
                    const float* __restrict__ c0,
                    const float* __restrict__ Wo,      // [3,H]
                    const float* __restrict__ bo,      // [3]
                    const uint2* __restrict__ Ma2,     // [64][256]
                    const float* __restrict__ v0,      // [256]
                    const uint4* __restrict__ Wc2,     // [264][256]
                    const float* __restrict__ bias_g,  // [1024]
                    float* __restrict__ pred_out,      // [B,N,3]
                    float* __restrict__ hid_out,       // [B,H]
                    float* __restrict__ attn_out)      // [B,N,S]
{
    const int b    = blockIdx.x;
    const int t    = threadIdx.x;
    const int wave = t >> 6;
    const int lane = t & 63;

    __shared__ __align__(16) float s_h[HID], s_c[HID];
    __shared__ __align__(16) u32   s_vqh[HID / 2];     // vq fp16 pairs
    __shared__ __align__(16) u32   s_wh[SEQ / 2];      // softmax w fp16 pairs
    __shared__ __align__(16) u32   s_xh[KP2];          // xcat2 fp16 pairs
    __shared__ __align__(16) float s_gp[4096];         // passB [16][256]; P5 [4][1024]
    __shared__ __align__(16) float s_wmax[16], s_wsum[16], s_pred[4];

    // ---- init ----
    if (t < HID) {
        const float hv = h0[b * HID + t];
        s_h[t] = hv;
        s_c[t] = c0[b * HID + t];
        const float hN = __shfl_xor(hv, 1);
        if (!(t & 1)) s_xh[130 + (t >> 1)] = pkrtz_(hv, hN);
    }
    if (t < 2) s_xh[t] = 0u;                       // SOS x_in pairs
    if (t >= 258 && t < KP2) s_xh[t] = 0u;         // zero pad pairs
    if (t < 4) s_pred[t] = 0.f;
    __syncthreads();

    const float* encb  = enc  + (size_t)b * SEQ * HID;
    const u32*   enchb = EH ? (ench + (size_t)b * SEQ * (HID / 2)) : nullptr;

    // prologue: vq for step 0
    if (t >= 256 && t < 512) p1_body(Ma2, v0, s_xh, s_vqh, t & 255);
    __syncthreads();

    for (int n = 0; n < NPRED; ++n) {
        // ---- [A] scores: 2 threads per row (K halves), fp16 dot2 ----
        const int r  = t >> 1;           // row 0..511
        const int hf = t & 1;            // K half
        float sa = 0.f, sb = 0.f;
        {
            const int base = (r << 7) + (hf << 6);
            #pragma unroll 4
            for (int i = 0; i < 16; ++i) {
                const uint4 e = ld4e_<EH>(enchb, encb, base + (i << 2));
                const uint4 v = *(const uint4*)&s_vqh[(hf << 6) + (i << 2)];
                sa = fdot2_(e.x, v.x, sa); sb = fdot2_(e.y, v.y, sb);
                sa = fdot2_(e.z, v.z, sa); sb = fdot2_(e.w, v.w, sb);
            }
        }
        float sc = sa + sb;
        sc += __shfl_xor(sc, 1);         // both K-halves -> full score (both lanes)
        // wave max over the 32 distinct rows (offs 2..32)
        float m = sc;
        m = fmaxf(m, __shfl_xor(m, 2));  m = fmaxf(m, __shfl_xor(m, 4));
        m = fmaxf(m, __shfl_xor(m, 8));  m = fmaxf(m, __shfl_xor(m, 16));
        m = fmaxf(m, __shfl_xor(m, 32));
        if (lane == 0) s_wmax[wave] = m;
        __syncthreads();                                     // b1

        // ---- [B] block max, exp, pack w pairs, wave sum ----
        float M;
        {
            const float4* q4 = (const float4*)s_wmax;
            float4 v = q4[0];
            M = fmaxf(fmaxf(v.x, v.y), fmaxf(v.z, v.w));
            #pragma unroll
            for (int w = 1; w < 4; ++w) {
                v = q4[w];
                M = fmaxf(M, fmaxf(fmaxf(v.x, v.y), fmaxf(v.z, v.w)));
            }
        }
        const float e = __expf(sc - M);
        {
            const float e2 = __shfl_xor(e, 2);   // next row's w
            if (!(t & 3)) s_wh[t >> 2] = pkrtz_(e, e2);
        }
        float su = e;
        su += __shfl_xor(su, 2);  su += __shfl_xor(su, 4);
        su += __shfl_xor(su, 8);  su += __shfl_xor(su, 16);
        su += __shfl_xor(su, 32);
        if (lane == 0) s_wsum[wave] = su;
        __syncthreads();                                     // b2

        // ---- [C] L, attn_out, weighted ctx partials (row pairs, perm+dot2) ----
        float L = 0.f;
        {
            const float4* q4 = (const float4*)s_wsum;
            #pragma unroll
            for (int w = 0; w < 4; ++w) {
                const float4 v = q4[w];
                L += (v.x + v.y) + (v.z + v.w);
            }
        }
        const float invL = 1.0f / L;
        if (!(t & 1))
            attn_out[((size_t)b * NPRED + n) * SEQ + r] = e * invL;

        {
            float4 cacc = {0.f, 0.f, 0.f, 0.f};
            #pragma unroll 4
            for (int i = 0; i < 16; ++i) {
                const int q  = wave + (i << 4);      // row pair index
                const int s0 = q << 1;
                const uint2 ea = ld2e_<EH>(enchb, encb, (s0 << 7) + (lane << 1));
                const uint2 eb = ld2e_<EH>(enchb, encb, ((s0 + 1) << 7) + (lane << 1));
                const u32 wp = s_wh[q];
                cacc.x = fdot2_(lo_lo(ea.x, eb.x), wp, cacc.x);
                cacc.y = fdot2_(hi_hi(ea.x, eb.x), wp, cacc.y);
                cacc.z = fdot2_(lo_lo(ea.y, eb.y), wp, cacc.z);
                cacc.w = fdot2_(hi_hi(ea.y, eb.y), wp, cacc.w);
            }
            *(float4*)&s_gp[(wave << 8) + (lane << 2)] = cacc;
        }
        __syncthreads();                                     // b3

        // ---- [D] ctx combine + pack; x_in pairs from prev pred ----
        if (t < HID) {
            float c = 0.f;
            #pragma unroll
            for (int w = 0; w < 16; ++w) c += s_gp[(w << 8) + t];
            c *= invL;
            const float cN = __shfl_xor(c, 1);
            if (!(t & 1)) s_xh[2 + (t >> 1)] = pkrtz_(c, cN);
        }
        if (t == 256) {
            s_xh[0] = pkrtz_(s_pred[0], s_pred[1]);
            s_xh[1] = pkrtz_(s_pred[2], 0.f);
        }
        __syncthreads();                                     // b4

        // ---- [E] gates GEMV: fp16 dot2, 4-way split over 66 k-pairs ----
        {
            const int j  = t & 255;
            const int ks = t >> 8;
            float4 g4 = {0.f, 0.f, 0.f, 0.f};
            const int pbeg = ks * 66;
            #pragma unroll 3
            for (int pp = 0; pp < 66; ++pp) {
                const int p = pbeg + pp;
                const uint4 w = Wc2[(p << 8) + j];
                const u32 x = s_xh[p];
                g4.x = fdot2_(w.x, x, g4.x);
                g4.y = fdot2_(w.y, x, g4.y);
                g4.z = fdot2_(w.z, x, g4.z);
                g4.w = fdot2_(w.w, x, g4.w);
            }
            *(float4*)&s_gp[(ks << 10) + (j << 2)] = g4;
        }
        __syncthreads();                                     // b5

        // ---- [F] gates finalize + LSTM pointwise; pack new h pairs ----
        if (t < HID) {
            float gv[4];
            #pragma unroll
            for (int q = 0; q < 4; ++q) {
                const int gi = (q << 8) + t;
                gv[q] = bias_g[gi] + s_gp[gi] + s_gp[1024 + gi]
                      + s_gp[2048 + gi] + s_gp[3072 + gi];
            }
            const float cn = sigmoidf_(gv[1]) * s_c[t] + sigmoidf_(gv[0]) * tanhf_(gv[2]);
            const float hn = sigmoidf_(gv[3]) * tanhf_(cn);
            s_c[t] = cn;
            s_h[t] = hn;
            const float hN = __shfl_xor(hn, 1);
            if (!(t & 1)) s_xh[130 + (t >> 1)] = pkrtz_(hn, hN);
        }
        __syncthreads();                                     // b6

        // ---- [G] pred (waves 0-2)  ||  vq for next step (waves 4-7) ----
        if (wave < NOUT) {
            const float4 w4 = *(const float4*)&Wo[wave * HID + (lane << 2)];
            const float4 h4 = *(const float4*)&s_h[lane << 2];
            float p = w4.x * h4.x + w4.y * h4.y + w4.z * h4.z + w4.w * h4.w;
            #pragma unroll
            for (int off = 32; off >= 1; off >>= 1) p += __shfl_xor(p, off);
            if (lane == 0) {
                p += bo[wave];
                s_pred[wave] = p;
                pred_out[((size_t)b * NPRED + n) * NOUT + wave] = p;
            }
        } else if (t >= 256 && t < 512 && n + 1 < NPRED) {
            p1_body(Ma2, v0, s_xh, s_vqh, t & 255);
        }
        __syncthreads();                                     // b7
    }

    if (t < HID) hid_out[b * HID + t] = s_h[t];
}

// ---------------------------------------------------------------------------
extern "C" void kernel_launch(void* const* d_in, const int* in_sizes, int n_in,
                              void* d_out, int out_size, void* d_ws, size_t ws_size,
                              hipStream_t stream) {
    const float* enc  = (const float*)d_in[0];
    const float* h0   = (const float*)d_in[1];
    const float* c0   = (const float*)d_in[2];
    const float* Wa   = (const float*)d_in[3];
    const float* ba   = (const float*)d_in[4];
    const float* Ua   = (const float*)d_in[5];
    // d_in[6] = bua: dropped — its score contribution is constant over s (softmax-invariant)
    const float* W_ih = (const float*)d_in[7];
    const float* W_hh = (const float*)d_in[8];
    const float* b_ih = (const float*)d_in[9];
    const float* b_hh = (const float*)d_in[10];
    const float* Wo   = (const float*)d_in[11];
    const float* bo   = (const float*)d_in[12];

    char* ws = (char*)d_ws;
    uint4* Wc2    = (uint4*)ws;                      ws += (size_t)KP2 * 256 * 16;  // 1,081,344
    uint2* Ma2    = (uint2*)ws;                      ws += (size_t)64 * 256 * 8;    //   131,072
    float* v0     = (float*)ws;                      ws += 256 * 4;
    float* bias_g = (float*)ws;                      ws += GATES * 4;
    const size_t base = (size_t)(ws - (char*)d_ws);
    const size_t ench_bytes = (size_t)BATCH * SEQ * HID * 2;   // 67,108,864
    const bool use_ench = ws_size >= base + ench_bytes;
    u32* ench = (u32*)ws;

    float* pred_out = (float*)d_out;                    // [B,N,3]
    float* hid_out  = pred_out + BATCH * NPRED * NOUT;  // [1,B,H]
    float* attn_out = hid_out + BATCH * HID;            // [B,N,S]

    prep_wc  <<<dim3(KP2), dim3(256),  0, stream>>>(W_ih, W_hh, Wc2);
    prep_ma  <<<dim3(64),  dim3(256),  0, stream>>>(Wa, Ua, Ma2);
    prep_misc<<<dim3(1),   dim3(1024), 0, stream>>>(b_ih, b_hh, ba, Ua, bias_g, v0);
    if (use_ench) {
        prep_ench<<<dim3(2048), dim3(256), 0, stream>>>(enc, ench);
        decoder_kernel<true><<<dim3(BATCH), dim3(1024), 0, stream>>>(
            enc, ench, h0, c0, Wo, bo, Ma2, v0, Wc2, bias_g,
            pred_out, hid_out, attn_out);
    } else {
        decoder_kernel<false><<<dim3(BATCH), dim3(1024), 0, stream>>>(
            enc, ench, h0, c0, Wo, bo, Ma2, v0, Wc2, bias_g,
            pred_out, hid_out, attn_out);
    }
}

// Round 3
// 1414.802 us; speedup vs baseline: 1.7396x; 1.6595x over previous
//
#include <hip/hip_runtime.h>
#include <math.h>

#define HID   256
#define SEQ   512
#define BATCH 256
#define NPRED 64
#define NOUT  3
#define KP2   264    // fp16 k-pairs of padded xcat2: [x0,x1,x2,0, ctx(256), h(256), pad] / 2
#define GATES 1024

typedef unsigned int u32;
typedef _Float16 half2_t __attribute__((ext_vector_type(2)));
typedef __fp16   fp16x2_t __attribute__((ext_vector_type(2)));

__device__ __forceinline__ float sigmoidf_(float x) { return 1.0f / (1.0f + __expf(-x)); }
__device__ __forceinline__ float tanhf_(float x)    { return 1.0f - 2.0f / (__expf(2.0f * x) + 1.0f); }

// ---- fp16 pack / dot / pk helpers -----------------------------------------
__device__ __forceinline__ float fdot2_(u32 a, u32 b, float c) {
#if __has_builtin(__builtin_amdgcn_fdot2)
    union { u32 u; half2_t h; } x, y; x.u = a; y.u = b;
    return __builtin_amdgcn_fdot2(x.h, y.h, c, false);
#else
    union { u32 u; _Float16 h[2]; } x, y; x.u = a; y.u = b;
    return c + (float)x.h[0] * (float)y.h[0] + (float)x.h[1] * (float)y.h[1];
#endif
}
__device__ __forceinline__ u32 pkrtz_(float a, float b) {
#if __has_builtin(__builtin_amdgcn_cvt_pkrtz)
    union { fp16x2_t h; u32 u; } c; c.h = __builtin_amdgcn_cvt_pkrtz(a, b); return c.u;
#else
    union { _Float16 h[2]; u32 u; } c; c.h[0] = (_Float16)a; c.h[1] = (_Float16)b; return c.u;
#endif
}
__device__ __forceinline__ u32 pkrne_(float a, float b) {   // RNE pack
    union { _Float16 h[2]; u32 u; } c; c.h[0] = (_Float16)a; c.h[1] = (_Float16)b; return c.u;
}
__device__ __forceinline__ u32 pkfma_(u32 a, u32 b, u32 c) {  // v_pk_fma_f16
    union { u32 u; half2_t h; } x, y, z, r; x.u = a; y.u = b; z.u = c;
    r.h = x.h * y.h + z.h;
    return r.u;
}
__device__ __forceinline__ u32 pkadd_(u32 a, u32 b) {
    union { u32 u; half2_t h; } x, y, r; x.u = a; y.u = b;
    r.h = x.h + y.h;
    return r.u;
}
__device__ __forceinline__ float lof_(u32 u) {
    union { u32 x; half2_t h; } c; c.x = u; return (float)c.h[0];
}
__device__ __forceinline__ float hif_(u32 u) {
    union { u32 x; half2_t h; } c; c.x = u; return (float)c.h[1];
}

// ---------------------------------------------------------------------------
// prep_wc: Wcat column for padded-xcat2 k:
//   k<3: W_ih[:,k] (x_in) | k==3: 0 | 4<=k<260: W_ih[:,k-1] (ctx) |
//   260<=k<516: W_hh[:,k-260] (h) | else 0.  fp16 pairs, comp q = gate 4j+q.
// ---------------------------------------------------------------------------
__device__ __forceinline__ float colval_(const float* W_ih, const float* W_hh, int g, int k) {
    if (k < 3)   return W_ih[g * 259 + k];
    if (k == 3)  return 0.f;
    if (k < 260) return W_ih[g * 259 + (k - 1)];
    if (k < 516) return W_hh[g * HID + (k - 260)];
    return 0.f;
}
__global__ void prep_wc(const float* __restrict__ W_ih,
                        const float* __restrict__ W_hh,
                        uint4* __restrict__ Wc2) {
    const int p = blockIdx.x;        // 0..263 k-pair
    const int j = threadIdx.x;       // 0..255
    u32 comp[4];
    #pragma unroll
    for (int q = 0; q < 4; ++q) {
        const int g = 4 * j + q;
        comp[q] = pkrne_(colval_(W_ih, W_hh, g, 2 * p),
                         colval_(W_ih, W_hh, g, 2 * p + 1));
    }
    Wc2[p * 256 + j] = make_uint4(comp[0], comp[1], comp[2], comp[3]);
}

// ---------------------------------------------------------------------------
// prep_ma: MaT[k][j] = sum_m Wa[m][k]*Ua[m][j]; fp16 pairs.
// ---------------------------------------------------------------------------
__global__ void prep_ma(const float* __restrict__ Wa,
                        const float* __restrict__ Ua,
                        uint2* __restrict__ Ma2) {
    const int k4 = blockIdx.x;       // 0..63
    const int j  = threadIdx.x;      // 0..255
    float acc[4] = {0.f, 0.f, 0.f, 0.f};
    for (int m = 0; m < HID; ++m) {
        const float ua = Ua[m * HID + j];
        #pragma unroll
        for (int q = 0; q < 4; ++q)
            acc[q] += Wa[m * HID + 4 * k4 + q] * ua;
    }
    Ma2[k4 * 256 + j] = make_uint2(pkrne_(acc[0], acc[1]), pkrne_(acc[2], acc[3]));
}

__global__ void prep_misc(const float* __restrict__ b_ih,
                          const float* __restrict__ b_hh,
                          const float* __restrict__ ba,
                          const float* __restrict__ Ua,
                          float* __restrict__ bias_g,
                          float* __restrict__ v0) {
    const int t = threadIdx.x;
    if (t < GATES) bias_g[t] = b_ih[t] + b_hh[t];
    if (t < HID) {
        float acc = 0.f;
        for (int m = 0; m < HID; ++m) acc += ba[m] * Ua[m * HID + t];
        v0[t] = acc;
    }
}

// ---- P1: vq[j] = v0[j] + sum_k MaT[k][j] h[k]; fp16 dot2, 256 threads -----
__device__ __forceinline__ void p1_body(const uint2* __restrict__ Ma2,
                                        const float* __restrict__ v0,
                                        const u32* s_xh, u32* s_vqh, int j) {
    float a0 = 0.f, a1 = 0.f;
    #pragma unroll 8
    for (int p2 = 0; p2 < 64; ++p2) {
        const uint2 ma = Ma2[(p2 << 8) + j];
        const uint2 hh = *(const uint2*)&s_xh[130 + (p2 << 1)];
        a0 = fdot2_(ma.x, hh.x, a0);
        a1 = fdot2_(ma.y, hh.y, a1);
    }
    float acc = v0[j] + a0 + a1;
    const float accN = __shfl_xor(acc, 1);
    if (!(j & 1)) s_vqh[j >> 1] = pkrtz_(acc, accN);
}

// ---------------------------------------------------------------------------
// Persistent decoder: one 1024-thread block per batch element.
// enc slice (512x256 fp16 = 256 KB) held ENTIRELY in registers:
//   thread t: rowgroup rg=t>>4 (8 rows), h-chunk hc=t&15 (8 fp16-pairs).
//   encR[rr*8+i] = (enc[rg*8+rr][hc*16+2i], enc[..][hc*16+2i+1])
// ---------------------------------------------------------------------------
__global__ __launch_bounds__(1024)
void decoder_kernel(const float* __restrict__ enc,     // [B,S,H] fp32
                    const float* __restrict__ h0,
                    const float* __restrict__ c0,
                    const float* __restrict__ Wo,      // [3,H]
                    const float* __restrict__ bo,      // [3]
                    const uint2* __restrict__ Ma2,     // [64][256]
                    const float* __restrict__ v0,      // [256]
                    const uint4* __restrict__ Wc2,     // [264][256]
                    const float* __restrict__ bias_g,  // [1024]
                    float* __restrict__ pred_out,      // [B,N,3]
                    float* __restrict__ hid_out,       // [B,H]
                    float* __restrict__ attn_out)      // [B,N,S]
{
    const int b    = blockIdx.x;
    const int t    = threadIdx.x;
    const int wave = t >> 6;
    const int lane = t & 63;
    const int rg   = t >> 4;          // 0..63 row group (8 rows each)
    const int hc   = t & 15;          // 0..15 h-chunk (16 cols = 8 pairs)

    __shared__ __align__(16) float s_h[HID], s_c[HID];
    __shared__ __align__(16) u32   s_vqh[HID / 2];     // vq fp16 pairs
    __shared__ __align__(16) u32   s_xh[KP2];          // xcat2 fp16 pairs
    __shared__ __align__(16) float s_gp[4096];         // C: u32[16][128]; E: f32[4][1024]
    __shared__ __align__(16) float s_wmax[16], s_wsum[16], s_pred[4];
    u32* const s_gpu = (u32*)s_gp;

    // ---- load enc slice into registers (once), fp32 -> fp16 RNE ----
    u32 encR[64];
    {
        const float* ep = enc + ((size_t)b * SEQ + rg * 8) * HID + hc * 16;
        #pragma unroll
        for (int rr = 0; rr < 8; ++rr) {
            #pragma unroll
            for (int i2 = 0; i2 < 4; ++i2) {
                const float4 f = *(const float4*)(ep + rr * HID + i2 * 4);
                encR[rr * 8 + i2 * 2]     = pkrne_(f.x, f.y);
                encR[rr * 8 + i2 * 2 + 1] = pkrne_(f.z, f.w);
            }
        }
    }

    // ---- init LDS state ----
    if (t < HID) {
        const float hv = h0[b * HID + t];
        s_h[t] = hv;
        s_c[t] = c0[b * HID + t];
        const float hN = __shfl_xor(hv, 1);
        if (!(t & 1)) s_xh[130 + (t >> 1)] = pkrtz_(hv, hN);
    }
    if (t < 2) s_xh[t] = 0u;                       // SOS x_in pairs
    if (t >= 258 && t < KP2) s_xh[t] = 0u;         // zero pad pairs
    if (t < 4) s_pred[t] = 0.f;
    __syncthreads();

    // prologue: vq for step 0
    if (t >= 256 && t < 512) p1_body(Ma2, v0, s_xh, s_vqh, t & 255);
    __syncthreads();

    for (int n = 0; n < NPRED; ++n) {
        // ---- [A] scores from registers: 8 rows x (16-col partial) ----
        float acc[8];
        {
            u32 vq[8];
            *(uint4*)&vq[0] = *(const uint4*)&s_vqh[hc * 8];
            *(uint4*)&vq[4] = *(const uint4*)&s_vqh[hc * 8 + 4];
            #pragma unroll
            for (int rr = 0; rr < 8; ++rr) {
                float a = 0.f;
                #pragma unroll
                for (int i = 0; i < 8; ++i) a = fdot2_(encR[rr * 8 + i], vq[i], a);
                acc[rr] = a;
            }
        }
        // reduce across the 16 h-chunk lanes (offsets 1..8)
        #pragma unroll
        for (int rr = 0; rr < 8; ++rr) {
            acc[rr] += __shfl_xor(acc[rr], 1);
            acc[rr] += __shfl_xor(acc[rr], 2);
            acc[rr] += __shfl_xor(acc[rr], 4);
            acc[rr] += __shfl_xor(acc[rr], 8);
        }
        // wave max (32 rows per wave)
        float mx = acc[0];
        #pragma unroll
        for (int rr = 1; rr < 8; ++rr) mx = fmaxf(mx, acc[rr]);
        mx = fmaxf(mx, __shfl_xor(mx, 16));
        mx = fmaxf(mx, __shfl_xor(mx, 32));
        if (lane == 0) s_wmax[wave] = mx;
        __syncthreads();                                     // b1

        // ---- [B] block max, exp, wave sum ----
        float M;
        {
            const float4* q4 = (const float4*)s_wmax;
            float4 v = q4[0];
            M = fmaxf(fmaxf(v.x, v.y), fmaxf(v.z, v.w));
            #pragma unroll
            for (int w = 1; w < 4; ++w) {
                v = q4[w];
                M = fmaxf(M, fmaxf(fmaxf(v.x, v.y), fmaxf(v.z, v.w)));
            }
        }
        float e[8];
        #pragma unroll
        for (int rr = 0; rr < 8; ++rr) e[rr] = __expf(acc[rr] - M);
        float su = e[0];
        #pragma unroll
        for (int rr = 1; rr < 8; ++rr) su += e[rr];
        su += __shfl_xor(su, 16);
        su += __shfl_xor(su, 32);
        if (lane == 0) s_wsum[wave] = su;
        __syncthreads();                                     // b2

        // ---- [C] invL, attn out, ctx accumulate from registers ----
        float L = 0.f;
        {
            const float4* q4 = (const float4*)s_wsum;
            #pragma unroll
            for (int w = 0; w < 4; ++w) {
                const float4 v = q4[w];
                L += (v.x + v.y) + (v.z + v.w);
            }
        }
        const float invL = 1.0f / L;
        if (hc == 0) {
            float* ap = attn_out + ((size_t)b * NPRED + n) * SEQ + rg * 8;
            float4 o0, o1;
            o0.x = e[0] * invL; o0.y = e[1] * invL; o0.z = e[2] * invL; o0.w = e[3] * invL;
            o1.x = e[4] * invL; o1.y = e[5] * invL; o1.z = e[6] * invL; o1.w = e[7] * invL;
            *(float4*)ap = o0; *(float4*)(ap + 4) = o1;
        }
        u32 wp[8];
        #pragma unroll
        for (int rr = 0; rr < 8; ++rr) {
            const float wn = e[rr] * invL;     // fold invL here
            wp[rr] = pkrne_(wn, wn);
        }
        u32 ah[8];
        #pragma unroll
        for (int i = 0; i < 8; ++i) ah[i] = 0u;
        #pragma unroll
        for (int rr = 0; rr < 8; ++rr) {
            #pragma unroll
            for (int i = 0; i < 8; ++i)
                ah[i] = pkfma_(encR[rr * 8 + i], wp[rr], ah[i]);
        }
        // reduce across 4 rowgroups within wave (offsets 16, 32)
        #pragma unroll
        for (int i = 0; i < 8; ++i) {
            u32 v = ah[i];
            v = pkadd_(v, (u32)__shfl_xor((int)v, 16));
            v = pkadd_(v, (u32)__shfl_xor((int)v, 32));
            ah[i] = v;
        }
        if ((lane >> 4) == 0) {   // one subgroup per wave writes the partial
            *(uint4*)&s_gpu[wave * 128 + hc * 8]     = *(const uint4*)&ah[0];
            *(uint4*)&s_gpu[wave * 128 + hc * 8 + 4] = *(const uint4*)&ah[4];
        }
        __syncthreads();                                     // b3

        // ---- [D] ctx combine (fp32) + pack; x_in pairs from prev pred ----
        if (t < 128) {
            float cx = 0.f, cy = 0.f;
            #pragma unroll
            for (int w = 0; w < 16; ++w) {
                const u32 u = s_gpu[w * 128 + t];
                cx += lof_(u);
                cy += hif_(u);
            }
            s_xh[2 + t] = pkrne_(cx, cy);
        }
        if (t == 256) {
            s_xh[0] = pkrtz_(s_pred[0], s_pred[1]);
            s_xh[1] = pkrtz_(s_pred[2], 0.f);
        }
        __syncthreads();                                     // b4

        // ---- [E] gates GEMV: fp16 dot2, 4-way split over 66 k-pairs ----
        {
            const int j  = t & 255;
            const int ks = t >> 8;
            float4 g4 = {0.f, 0.f, 0.f, 0.f};
            const int pbeg = ks * 66;
            #pragma unroll 3
            for (int pp = 0; pp < 66; ++pp) {
                const int p = pbeg + pp;
                const uint4 w = Wc2[(p << 8) + j];
                const u32 x = s_xh[p];
                g4.x = fdot2_(w.x, x, g4.x);
                g4.y = fdot2_(w.y, x, g4.y);
                g4.z = fdot2_(w.z, x, g4.z);
                g4.w = fdot2_(w.w, x, g4.w);
            }
            *(float4*)&s_gp[(ks << 10) + (j << 2)] = g4;
        }
        __syncthreads();                                     // b5

        // ---- [F] gates finalize + LSTM pointwise; pack new h pairs ----
        if (t < HID) {
            float gv[4];
            #pragma unroll
            for (int q = 0; q < 4; ++q) {
                const int gi = (q << 8) + t;
                gv[q] = bias_g[gi] + s_gp[gi] + s_gp[1024 + gi]
                      + s_gp[2048 + gi] + s_gp[3072 + gi];
            }
            const float cn = sigmoidf_(gv[1]) * s_c[t] + sigmoidf_(gv[0]) * tanhf_(gv[2]);
            const float hn = sigmoidf_(gv[3]) * tanhf_(cn);
            s_c[t] = cn;
            s_h[t] = hn;
            const float hN = __shfl_xor(hn, 1);
            if (!(t & 1)) s_xh[130 + (t >> 1)] = pkrtz_(hn, hN);
        }
        __syncthreads();                                     // b6

        // ---- [G] pred (waves 0-2)  ||  vq for next step (waves 4-7) ----
        if (wave < NOUT) {
            const float4 w4 = *(const float4*)&Wo[wave * HID + (lane << 2)];
            const float4 h4 = *(const float4*)&s_h[lane << 2];
            float p = w4.x * h4.x + w4.y * h4.y + w4.z * h4.z + w4.w * h4.w;
            #pragma unroll
            for (int off = 32; off >= 1; off >>= 1) p += __shfl_xor(p, off);
            if (lane == 0) {
                p += bo[wave];
                s_pred[wave] = p;
                pred_out[((size_t)b * NPRED + n) * NOUT + wave] = p;
            }
        } else if (t >= 256 && t < 512 && n + 1 < NPRED) {
            p1_body(Ma2, v0, s_xh, s_vqh, t & 255);
        }
        __syncthreads();                                     // b7
    }

    if (t < HID) hid_out[b * HID + t] = s_h[t];
}

// ---------------------------------------------------------------------------
extern "C" void kernel_launch(void* const* d_in, const int* in_sizes, int n_in,
                              void* d_out, int out_size, void* d_ws, size_t ws_size,
                              hipStream_t stream) {
    const float* enc  = (const float*)d_in[0];
    const float* h0   = (const float*)d_in[1];
    const float* c0   = (const float*)d_in[2];
    const float* Wa   = (const float*)d_in[3];
    const float* ba   = (const float*)d_in[4];
    const float* Ua   = (const float*)d_in[5];
    // d_in[6] = bua: dropped — its score contribution is constant over s (softmax-invariant)
    const float* W_ih = (const float*)d_in[7];
    const float* W_hh = (const float*)d_in[8];
    const float* b_ih = (const float*)d_in[9];
    const float* b_hh = (const float*)d_in[10];
    const float* Wo   = (const float*)d_in[11];
    const float* bo   = (const float*)d_in[12];

    char* ws = (char*)d_ws;
    uint4* Wc2    = (uint4*)ws;                      ws += (size_t)KP2 * 256 * 16;  // 1,081,344
    uint2* Ma2    = (uint2*)ws;                      ws += (size_t)64 * 256 * 8;    //   131,072
    float* v0     = (float*)ws;                      ws += 256 * 4;
    float* bias_g = (float*)ws;                      ws += GATES * 4;
    (void)ws_size;

    float* pred_out = (float*)d_out;                    // [B,N,3]
    float* hid_out  = pred_out + BATCH * NPRED * NOUT;  // [1,B,H]
    float* attn_out = hid_out + BATCH * HID;            // [B,N,S]

    prep_wc  <<<dim3(KP2), dim3(256),  0, stream>>>(W_ih, W_hh, Wc2);
    prep_ma  <<<dim3(64),  dim3(256),  0, stream>>>(Wa, Ua, Ma2);
    prep_misc<<<dim3(1),   dim3(1024), 0, stream>>>(b_ih, b_hh, ba, Ua, bias_g, v0);
    decoder_kernel<<<dim3(BATCH), dim3(1024), 0, stream>>>(
        enc, h0, c0, Wo, bo, Ma2, v0, Wc2, bias_g,
        pred_out, hid_out, attn_out);
}